// Round 5
// baseline (130.362 us; speedup 1.0000x reference)
//
#include <hip/hip_runtime.h>
#include <hip/hip_bf16.h>

#define N_NODES 50000
#define N_EDGES 640000
#define MAXDEG 64

typedef __attribute__((ext_vector_type(8))) short bf16x8;
typedef __attribute__((ext_vector_type(4))) float f32x4;

static __device__ __forceinline__ short f2bf(float f) {
    __hip_bfloat16 h = __float2bfloat16(f);
    return *reinterpret_cast<const short*>(&h);
}

// ---------------- Phase 1: bucket build (reverse adjacency) ----------------
__global__ __launch_bounds__(256)
void bucket_kernel(const int* __restrict__ ei,
                   unsigned int* __restrict__ counts,
                   unsigned int* __restrict__ bucket)
{
    const int e = blockIdx.x * 256 + threadIdx.x;
    if (e >= N_EDGES) return;
    const int dst = ei[N_EDGES + e];
    const unsigned int pos = atomicAdd(counts + dst, 1u);
    if (pos < MAXDEG) bucket[(size_t)dst * MAXDEG + pos] = (unsigned int)e;
}

// ---------------- Phase 2: per-edge features (NO atomics) ----------------
__global__ __launch_bounds__(256)
void edge_hyper_kernel(const float* __restrict__ x,
                       const int* __restrict__ ei,      // int32 [2][E]
                       const float* __restrict__ ev,
                       const float* __restrict__ nrm,
                       const float* __restrict__ W1,
                       const float* __restrict__ b1,
                       const float* __restrict__ W2,
                       const float* __restrict__ b2,
                       unsigned short* __restrict__ ftr, // bf16 [E][16]
                       int ngroups)
{
    __shared__ float h_lds[4][17][16];

    const int tid  = threadIdx.x;
    const int wv   = tid >> 6;       // wave in block
    const int l    = tid & 63;       // lane
    const int r    = l & 15;         // A-row edge index in group / output col o
    const int half = l >> 4;         // 0..3

    // ---- B fragments: 17 c-tiles (c=0..15 from W2, c=16 = bias b2) ----
    bf16x8 bfrag[17];
    {
        const int koff = half * 8;
        #pragma unroll
        for (int c = 0; c < 16; ++c) {
            const float* p = W2 + c * 512 + r * 32 + koff;
            bf16x8 t;
            #pragma unroll
            for (int j = 0; j < 8; ++j) t[j] = f2bf(p[j]);
            bfrag[c] = t;
        }
        const float* p = b2 + r * 32 + koff;
        bf16x8 t;
        #pragma unroll
        for (int j = 0; j < 8; ++j) t[j] = f2bf(p[j]);
        bfrag[16] = t;
    }

    float w1v0[4], w1v1[4], w1v2[4], b1v[4];
    #pragma unroll
    for (int q = 0; q < 4; ++q) {
        const int c = half * 4 + q;
        w1v0[q] = W1[c];
        w1v1[q] = W1[16 + c];
        w1v2[q] = W1[32 + c];
        b1v[q]  = b1[c];
    }

    if (half == 0) h_lds[wv][16][r] = 1.0f;

    const int gw = blockIdx.x * 4 + wv;
    const int nw = gridDim.x * 4;
    if (gw >= ngroups) return;

    // ---- software-pipeline prologue ----
    int g = gw;
    int    idx_c;
    float  v0_c, v1_c, v2_c;
    float4 xa_c, xb_c, nr_c;
    {
        const int e0 = g * 16;
        idx_c = ei[(half >= 2 ? N_EDGES : 0) + e0 + r];
        v0_c  = ev[(e0 + r) * 3 + 0];
        v1_c  = ev[(e0 + r) * 3 + 1];
        v2_c  = ev[(e0 + r) * 3 + 2];
        nr_c  = *reinterpret_cast<const float4*>(nrm + e0 + half * 4);
        const float4* xr = reinterpret_cast<const float4*>(
            x + (size_t)idx_c * 16 + (half & 1) * 8);
        xa_c = xr[0];
        xb_c = xr[1];
    }

    while (g < ngroups) {
        const int e0   = g * 16;
        const int gn   = g + nw;
        const bool hasn = gn < ngroups;

        // ---- issue NEXT group's independent loads ----
        int    idx_n = 0;
        float  v0_n = 0.f, v1_n = 0.f, v2_n = 0.f;
        float4 nr_n = {0.f, 0.f, 0.f, 0.f};
        if (hasn) {
            const int e0n = gn * 16;
            idx_n = ei[(half >= 2 ? N_EDGES : 0) + e0n + r];
            v0_n  = ev[(e0n + r) * 3 + 0];
            v1_n  = ev[(e0n + r) * 3 + 1];
            v2_n  = ev[(e0n + r) * 3 + 2];
            nr_n  = *reinterpret_cast<const float4*>(nrm + e0n + half * 4);
        }

        // ---- hypernetwork h = relu(ev@W1 + b1), exact f32 ----
        asm volatile("s_waitcnt lgkmcnt(0)" ::: "memory");
        #pragma unroll
        for (int q = 0; q < 4; ++q) {
            float hv = b1v[q] + v0_c * w1v0[q] + v1_c * w1v1[q] + v2_c * w1v2[q];
            h_lds[wv][half * 4 + q][r] = fmaxf(hv, 0.0f);
        }

        // ---- A fragment (xe in bf16) ----
        bf16x8 afrag;
        afrag[0] = f2bf(xa_c.x); afrag[1] = f2bf(xa_c.y);
        afrag[2] = f2bf(xa_c.z); afrag[3] = f2bf(xa_c.w);
        afrag[4] = f2bf(xb_c.x); afrag[5] = f2bf(xb_c.y);
        afrag[6] = f2bf(xb_c.z); afrag[7] = f2bf(xb_c.w);

        // ---- issue NEXT group's dependent x gather ----
        float4 xa_n = {0.f,0.f,0.f,0.f}, xb_n = {0.f,0.f,0.f,0.f};
        if (hasn) {
            const float4* xr = reinterpret_cast<const float4*>(
                x + (size_t)idx_n * 16 + (half & 1) * 8);
            xa_n = xr[0];
            xb_n = xr[1];
        }

        asm volatile("s_waitcnt lgkmcnt(0)" ::: "memory");

        // ---- T = XE @ W2c per c-tile (MFMA), contract with h on VALU ----
        float s0 = 0.f, s1 = 0.f, s2 = 0.f, s3 = 0.f;
        #pragma unroll
        for (int c = 0; c < 17; ++c) {
            f32x4 t = __builtin_amdgcn_mfma_f32_16x16x32_bf16(
                afrag, bfrag[c], (f32x4){0.f, 0.f, 0.f, 0.f}, 0, 0, 0);
            const float4 h4 = *reinterpret_cast<const float4*>(
                &h_lds[wv][c][half * 4]);
            s0 += h4.x * t[0];
            s1 += h4.y * t[1];
            s2 += h4.z * t[2];
            s3 += h4.w * t[3];
        }

        // ---- epilogue: tanh, norm scale, bf16 store to ftr ----
        const float nrv[4] = {nr_c.x, nr_c.y, nr_c.z, nr_c.w};
        const float sv[4]  = {s0, s1, s2, s3};
        #pragma unroll
        for (int q = 0; q < 4; ++q) {
            const float s = sv[q];
            const float t = __expf(-2.0f * fabsf(s));
            float th = (1.0f - t) / (1.0f + t);
            th = copysignf(th, s);
            const float val = th * nrv[q];
            const int e = e0 + half * 4 + q;
            ftr[(size_t)e * 16 + r] = (unsigned short)f2bf(val);
        }

        // ---- rotate pipeline state ----
        idx_c = idx_n;
        v0_c = v0_n; v1_c = v1_n; v2_c = v2_n;
        nr_c = nr_n;
        xa_c = xa_n; xb_c = xb_n;
        g = gn;
    }
}

// ---------------- Phase 3: gather-reduce per destination node ----------------
__global__ __launch_bounds__(256)
void gather_kernel(const unsigned short* __restrict__ ftr,
                   const unsigned int* __restrict__ bucket,
                   const unsigned int* __restrict__ counts,
                   float* __restrict__ out)
{
    const int tid  = threadIdx.x;
    const int r    = tid & 15;
    const int node = blockIdx.x * 16 + (tid >> 4);
    if (node >= N_NODES) return;

    unsigned int cnt = counts[node];
    if (cnt > MAXDEG) cnt = MAXDEG;
    const unsigned int* brow = bucket + (size_t)node * MAXDEG;

    float acc = 0.f;
    unsigned int j = 0;
    for (; j + 4 <= cnt; j += 4) {
        const unsigned int ea = brow[j + 0];
        const unsigned int eb = brow[j + 1];
        const unsigned int ec = brow[j + 2];
        const unsigned int ed = brow[j + 3];
        const unsigned int ua = ftr[(size_t)ea * 16 + r];
        const unsigned int ub = ftr[(size_t)eb * 16 + r];
        const unsigned int uc = ftr[(size_t)ec * 16 + r];
        const unsigned int ud = ftr[(size_t)ed * 16 + r];
        float va, vb, vc, vd;
        *(unsigned int*)&va = ua << 16;
        *(unsigned int*)&vb = ub << 16;
        *(unsigned int*)&vc = uc << 16;
        *(unsigned int*)&vd = ud << 16;
        acc += (va + vb) + (vc + vd);
    }
    for (; j < cnt; ++j) {
        const unsigned int e = brow[j];
        const unsigned int u = ftr[(size_t)e * 16 + r];
        float v;
        *(unsigned int*)&v = u << 16;
        acc += v;
    }
    out[(size_t)node * 16 + r] = acc;
}

// ---------------- fallback: single-kernel f32-atomic path (R4) ----------------
__global__ __launch_bounds__(256)
void edge_hyper_atomic_kernel(const float* __restrict__ x,
                              const int* __restrict__ ei,
                              const float* __restrict__ ev,
                              const float* __restrict__ nrm,
                              const float* __restrict__ W1,
                              const float* __restrict__ b1,
                              const float* __restrict__ W2,
                              const float* __restrict__ b2,
                              float* __restrict__ out,
                              int ngroups)
{
    __shared__ float h_lds[4][17][16];
    const int tid  = threadIdx.x;
    const int wv   = tid >> 6;
    const int l    = tid & 63;
    const int r    = l & 15;
    const int half = l >> 4;

    bf16x8 bfrag[17];
    {
        const int koff = half * 8;
        #pragma unroll
        for (int c = 0; c < 16; ++c) {
            const float* p = W2 + c * 512 + r * 32 + koff;
            bf16x8 t;
            #pragma unroll
            for (int j = 0; j < 8; ++j) t[j] = f2bf(p[j]);
            bfrag[c] = t;
        }
        const float* p = b2 + r * 32 + koff;
        bf16x8 t;
        #pragma unroll
        for (int j = 0; j < 8; ++j) t[j] = f2bf(p[j]);
        bfrag[16] = t;
    }
    float w1v0[4], w1v1[4], w1v2[4], b1v[4];
    #pragma unroll
    for (int q = 0; q < 4; ++q) {
        const int c = half * 4 + q;
        w1v0[q] = W1[c]; w1v1[q] = W1[16 + c];
        w1v2[q] = W1[32 + c]; b1v[q] = b1[c];
    }
    if (half == 0) h_lds[wv][16][r] = 1.0f;

    for (int g = blockIdx.x * 4 + wv; g < ngroups; g += gridDim.x * 4) {
        const int e0 = g * 16;
        const int eg = e0 + r;
        const int idx = ei[(half >= 2 ? N_EDGES : 0) + eg];
        const float4* xr = reinterpret_cast<const float4*>(
            x + (size_t)idx * 16 + (half & 1) * 8);
        const float4 xa = xr[0];
        const float4 xb = xr[1];
        const float v0 = ev[eg * 3 + 0];
        const float v1 = ev[eg * 3 + 1];
        const float v2 = ev[eg * 3 + 2];
        asm volatile("s_waitcnt lgkmcnt(0)" ::: "memory");
        #pragma unroll
        for (int q = 0; q < 4; ++q) {
            float hv = b1v[q] + v0 * w1v0[q] + v1 * w1v1[q] + v2 * w1v2[q];
            h_lds[wv][half * 4 + q][r] = fmaxf(hv, 0.0f);
        }
        bf16x8 afrag;
        afrag[0] = f2bf(xa.x); afrag[1] = f2bf(xa.y);
        afrag[2] = f2bf(xa.z); afrag[3] = f2bf(xa.w);
        afrag[4] = f2bf(xb.x); afrag[5] = f2bf(xb.y);
        afrag[6] = f2bf(xb.z); afrag[7] = f2bf(xb.w);
        asm volatile("s_waitcnt lgkmcnt(0)" ::: "memory");
        float s0 = 0.f, s1 = 0.f, s2 = 0.f, s3 = 0.f;
        #pragma unroll
        for (int c = 0; c < 17; ++c) {
            f32x4 t = __builtin_amdgcn_mfma_f32_16x16x32_bf16(
                afrag, bfrag[c], (f32x4){0.f, 0.f, 0.f, 0.f}, 0, 0, 0);
            const float4 h4 = *reinterpret_cast<const float4*>(
                &h_lds[wv][c][half * 4]);
            s0 += h4.x * t[0]; s1 += h4.y * t[1];
            s2 += h4.z * t[2]; s3 += h4.w * t[3];
        }
        float sv[4] = {s0, s1, s2, s3};
        #pragma unroll
        for (int q = 0; q < 4; ++q) {
            const int e = e0 + half * 4 + q;
            const float s = sv[q];
            const float t = __expf(-2.0f * fabsf(s));
            float th = (1.0f - t) / (1.0f + t);
            th = copysignf(th, s);
            atomicAdd(out + (size_t)ei[N_EDGES + e] * 16 + r, th * nrm[e]);
        }
    }
}

extern "C" void kernel_launch(void* const* d_in, const int* in_sizes, int n_in,
                              void* d_out, int out_size, void* d_ws, size_t ws_size,
                              hipStream_t stream) {
    const float* x   = (const float*)d_in[0];
    const int*   ei  = (const int*)d_in[1];
    const float* ev  = (const float*)d_in[2];
    const float* nrm = (const float*)d_in[3];
    const float* W1  = (const float*)d_in[4];
    const float* b1  = (const float*)d_in[5];
    const float* W2  = (const float*)d_in[6];
    const float* b2  = (const float*)d_in[7];
    float* out = (float*)d_out;

    const int ngroups = N_EDGES / 16;   // 40000, exact

    // workspace layout
    const size_t FTR_BYTES = (size_t)N_EDGES * 16 * 2;          // 20,480,000
    const size_t BKT_OFF   = FTR_BYTES;                          // 256-aligned
    const size_t BKT_BYTES = (size_t)N_NODES * MAXDEG * 4;       // 12,800,000
    const size_t CNT_OFF   = BKT_OFF + BKT_BYTES;
    const size_t CNT_BYTES = (size_t)N_NODES * 4;
    const size_t TOTAL     = CNT_OFF + CNT_BYTES;                // 33,480,000

    if (ws_size >= TOTAL) {
        unsigned short* ftr    = (unsigned short*)d_ws;
        unsigned int*   bucket = (unsigned int*)((char*)d_ws + BKT_OFF);
        unsigned int*   counts = (unsigned int*)((char*)d_ws + CNT_OFF);

        hipMemsetAsync(counts, 0, CNT_BYTES, stream);
        hipLaunchKernelGGL(bucket_kernel,
                           dim3((N_EDGES + 255) / 256), dim3(256), 0, stream,
                           ei, counts, bucket);
        hipLaunchKernelGGL(edge_hyper_kernel,
                           dim3(2048), dim3(256), 0, stream,
                           x, ei, ev, nrm, W1, b1, W2, b2, ftr, ngroups);
        hipLaunchKernelGGL(gather_kernel,
                           dim3((N_NODES + 15) / 16), dim3(256), 0, stream,
                           ftr, bucket, counts, out);
    } else {
        hipMemsetAsync(out, 0, (size_t)out_size * sizeof(float), stream);
        hipLaunchKernelGGL(edge_hyper_atomic_kernel,
                           dim3(2048), dim3(256), 0, stream,
                           x, ei, ev, nrm, W1, b1, W2, b2, out, ngroups);
    }
}

// Round 6
// 60.300 us; speedup vs baseline: 2.1619x; 2.1619x over previous
//
#include <hip/hip_runtime.h>
#include <hip/hip_bf16.h>

#define N_NODES 50000
#define N_EDGES 640000

typedef __attribute__((ext_vector_type(8))) short bf16x8;
typedef __attribute__((ext_vector_type(4))) float f32x4;

static __device__ __forceinline__ short f2bf(float f) {
    __hip_bfloat16 h = __float2bfloat16(f);
    return *reinterpret_cast<const short*>(&h);
}

static __device__ __forceinline__ float sgpr_f(const float* p) {
    return __uint_as_float(__builtin_amdgcn_readfirstlane(__float_as_uint(*p)));
}

__global__ __launch_bounds__(256)
void edge_hyper_kernel(const float* __restrict__ x,
                       const int* __restrict__ ei,      // int32 [2][E]
                       const float* __restrict__ ev,
                       const float* __restrict__ nrm,
                       const float* __restrict__ W1,
                       const float* __restrict__ b1,
                       const float* __restrict__ W2,
                       const float* __restrict__ b2,
                       float* __restrict__ out,
                       int ngroups)
{
    // B tiles in LDS: [c][o][k] bf16, k-row padded 32->34 (68B stride) so the
    // 64 lanes' 16B reads start at ~2-way-aliased banks (2-way is free, m136).
    __shared__ short w2s[17 * 16 * 34];

    const int tid  = threadIdx.x;
    const int l    = tid & 63;
    const int r    = l & 15;         // output col o / A-row
    const int half = l >> 4;         // 0..3 -> k-range half*8..half*8+7

    // ---- cooperative W2/b2 -> bf16 LDS (c=16 is the b2 bias tile) ----
    for (int idx = tid; idx < 17 * 512; idx += 256) {
        const int c   = idx >> 9;
        const int rem = idx & 511;
        const int o   = rem >> 5;
        const int k   = rem & 31;
        const float v = (c < 16) ? W2[c * 512 + o * 32 + k] : b2[o * 32 + k];
        w2s[(c * 16 + o) * 34 + k] = f2bf(v);
    }

    // ---- W1/b1 pinned to SGPRs (uniform; readfirstlane forces scalar) ----
    float w1c0[16], w1c1[16], w1c2[16], b1s[16];
    #pragma unroll
    for (int c = 0; c < 16; ++c) {
        w1c0[c] = sgpr_f(W1 + c);
        w1c1[c] = sgpr_f(W1 + 16 + c);
        w1c2[c] = sgpr_f(W1 + 32 + c);
        b1s[c]  = sgpr_f(b1 + c);
    }

    __syncthreads();   // w2s ready; NO further sync anywhere

    // per-lane LDS base for B-fragment reads: element (c*16+r)*34 + half*8
    const short* wbase = &w2s[r * 34 + half * 8];   // + c*544 per tile

    const int wv = tid >> 6;
    int g = blockIdx.x * 4 + wv;
    const int nw = gridDim.x * 4;
    if (g >= ngroups) return;   // never taken at grid=2048, but safe (after sync)

    // ---- software-pipeline prologue (ei -> x chain + nrm + dst) ----
    int    idx_c;
    float4 xa_c, xb_c, nr_c;
    int4   dst_c;
    {
        const int e0 = g * 16;
        idx_c = ei[(half >= 2 ? N_EDGES : 0) + e0 + r];
        nr_c  = *reinterpret_cast<const float4*>(nrm + e0 + half * 4);
        dst_c = *reinterpret_cast<const int4*>(ei + N_EDGES + e0 + half * 4);
        const float4* xr = reinterpret_cast<const float4*>(
            x + (size_t)idx_c * 16 + (half & 1) * 8);
        xa_c = xr[0];
        xb_c = xr[1];
    }

    while (g < ngroups) {
        const int gn   = g + nw;
        const bool hasn = gn < ngroups;
        const int e0   = g * 16;

        // ---- current group's ev: 48B contiguous, this lane's 4 edges ----
        // edge q (= e0+half*4+q), component j lives at flat[q*3+j]
        const float4* evp = reinterpret_cast<const float4*>(
            ev + (size_t)e0 * 3 + half * 12);
        const float4 ea = evp[0];
        const float4 eb = evp[1];
        const float4 ec = evp[2];

        // ---- issue NEXT group's independent loads ----
        int    idx_n = 0;
        float4 nr_n = {0.f, 0.f, 0.f, 0.f};
        int4   dst_n = {0, 0, 0, 0};
        if (hasn) {
            const int e0n = gn * 16;
            idx_n = ei[(half >= 2 ? N_EDGES : 0) + e0n + r];
            nr_n  = *reinterpret_cast<const float4*>(nrm + e0n + half * 4);
            dst_n = *reinterpret_cast<const int4*>(ei + N_EDGES + e0n + half * 4);
        }

        // ---- A fragment (xe in bf16): row r, k = half*8+j ----
        bf16x8 afrag;
        afrag[0] = f2bf(xa_c.x); afrag[1] = f2bf(xa_c.y);
        afrag[2] = f2bf(xa_c.z); afrag[3] = f2bf(xa_c.w);
        afrag[4] = f2bf(xb_c.x); afrag[5] = f2bf(xb_c.y);
        afrag[6] = f2bf(xb_c.z); afrag[7] = f2bf(xb_c.w);

        // ---- issue NEXT group's dependent x gather (hides under c-loop) ----
        float4 xa_n = {0.f,0.f,0.f,0.f}, xb_n = {0.f,0.f,0.f,0.f};
        if (hasn) {
            const float4* xr = reinterpret_cast<const float4*>(
                x + (size_t)idx_n * 16 + (half & 1) * 8);
            xa_n = xr[0];
            xb_n = xr[1];
        }

        // ---- bias tile (c=16, h==1) initializes the accumulator ----
        f32x4 s;
        {
            const bf16x8 bfr = *reinterpret_cast<const bf16x8*>(wbase + 16 * 544);
            s = __builtin_amdgcn_mfma_f32_16x16x32_bf16(
                afrag, bfr, (f32x4){0.f, 0.f, 0.f, 0.f}, 0, 0, 0);
        }

        // per-edge ev components for this lane's 4 edges (const-indexed)
        const float ev0[4] = {ea.x, ea.w, eb.z, ec.y};
        const float ev1[4] = {ea.y, eb.x, eb.w, ec.z};
        const float ev2[4] = {ea.z, eb.y, ec.x, ec.w};

        // ---- 16 c-tiles: MFMA (T = XE@W2c^T) + inline h + contraction ----
        // D layout (m89-verified): col = l&15 (=o), row = (l>>4)*4 + reg (=edge)
        #pragma unroll
        for (int c = 0; c < 16; ++c) {
            const bf16x8 bfr = *reinterpret_cast<const bf16x8*>(wbase + c * 544);
            f32x4 t = __builtin_amdgcn_mfma_f32_16x16x32_bf16(
                afrag, bfr, (f32x4){0.f, 0.f, 0.f, 0.f}, 0, 0, 0);
            #pragma unroll
            for (int q = 0; q < 4; ++q) {
                float hv = fmaf(ev2[q], w1c2[c],
                           fmaf(ev1[q], w1c1[c],
                           fmaf(ev0[q], w1c0[c], b1s[c])));
                hv = fmaxf(hv, 0.0f);
                s[q] = fmaf(hv, t[q], s[q]);
            }
        }

        // ---- epilogue: fast tanh, norm scale, f32 scatter-add ----
        const float nrv[4] = {nr_c.x, nr_c.y, nr_c.z, nr_c.w};
        const int   dsv[4] = {dst_c.x, dst_c.y, dst_c.z, dst_c.w};
        #pragma unroll
        for (int q = 0; q < 4; ++q) {
            const float sv = s[q];
            const float t  = __expf(-2.0f * fabsf(sv));
            const float th = copysignf((1.0f - t) * __builtin_amdgcn_rcpf(1.0f + t), sv);
            atomicAdd(out + (size_t)dsv[q] * 16 + r, th * nrv[q]);
        }

        // ---- rotate pipeline state ----
        idx_c = idx_n;
        nr_c  = nr_n;
        dst_c = dst_n;
        xa_c  = xa_n;
        xb_c  = xb_n;
        g = gn;
    }
}

extern "C" void kernel_launch(void* const* d_in, const int* in_sizes, int n_in,
                              void* d_out, int out_size, void* d_ws, size_t ws_size,
                              hipStream_t stream) {
    const float* x   = (const float*)d_in[0];
    const int*   ei  = (const int*)d_in[1];     // harness delivers ints as int32
    const float* ev  = (const float*)d_in[2];
    const float* nrm = (const float*)d_in[3];
    const float* W1  = (const float*)d_in[4];
    const float* b1  = (const float*)d_in[5];
    const float* W2  = (const float*)d_in[6];
    const float* b2  = (const float*)d_in[7];
    float* out = (float*)d_out;

    hipMemsetAsync(out, 0, (size_t)out_size * sizeof(float), stream);

    const int ngroups = N_EDGES / 16;   // 40000, exact
    dim3 grid(2048), block(256);
    hipLaunchKernelGGL(edge_hyper_kernel, grid, block, 0, stream,
                       x, ei, ev, nrm, W1, b1, W2, b2, out, ngroups);
}

// Round 7
// 58.491 us; speedup vs baseline: 2.2288x; 1.0309x over previous
//
#include <hip/hip_runtime.h>
#include <hip/hip_bf16.h>

#define N_NODES 50000
#define N_EDGES 640000

typedef __attribute__((ext_vector_type(8))) short bf16x8;
typedef __attribute__((ext_vector_type(4))) float f32x4;

static __device__ __forceinline__ short f2bf(float f) {
    __hip_bfloat16 h = __float2bfloat16(f);
    return *reinterpret_cast<const short*>(&h);
}

static __device__ __forceinline__ float sgpr_f(const float* p) {
    return __uint_as_float(__builtin_amdgcn_readfirstlane(__float_as_uint(*p)));
}

__global__ __launch_bounds__(256)
void edge_hyper_kernel(const float* __restrict__ x,
                       const int* __restrict__ ei,      // int32 [2][E]
                       const float* __restrict__ ev,
                       const float* __restrict__ nrm,
                       const float* __restrict__ W1,
                       const float* __restrict__ b1,
                       const float* __restrict__ W2,
                       const float* __restrict__ b2,
                       float* __restrict__ out,
                       int ngroups)
{
    // B tiles in LDS: [c][o][k] bf16, k-row padded 32->34 (2-way aliasing free).
    __shared__ short w2s[17 * 16 * 34];

    const int tid  = threadIdx.x;
    const int l    = tid & 63;
    const int r    = l & 15;         // A-row edge-in-group / D col o
    const int half = l >> 4;         // 0..3 -> k-range half*8..half*8+7

    // ---- cooperative W2/b2 -> bf16 LDS (c=16 is the b2 bias tile) ----
    for (int idx = tid; idx < 17 * 512; idx += 256) {
        const int c   = idx >> 9;
        const int rem = idx & 511;
        const int o   = rem >> 5;
        const int k   = rem & 31;
        const float v = (c < 16) ? W2[c * 512 + o * 32 + k] : b2[o * 32 + k];
        w2s[(c * 16 + o) * 34 + k] = f2bf(v);
    }

    // ---- W1/b1 pinned to SGPRs ----
    float w1c0[16], w1c1[16], w1c2[16], b1s[16];
    #pragma unroll
    for (int c = 0; c < 16; ++c) {
        w1c0[c] = sgpr_f(W1 + c);
        w1c1[c] = sgpr_f(W1 + 16 + c);
        w1c2[c] = sgpr_f(W1 + 32 + c);
        b1s[c]  = sgpr_f(b1 + c);
    }

    __syncthreads();   // w2s ready; no further sync

    // per-lane LDS base: tile c element (c*16+r)*34 + half*8  ->  wbase + c*544
    const short* wbase = &w2s[r * 34 + half * 8];

    const int wv = tid >> 6;
    int g = blockIdx.x * 4 + wv;
    const int nw = gridDim.x * 4;
    if (g >= ngroups) return;

    // ---- software-pipeline prologue: edge r's idx/ev, epilogue's nrm/dst ----
    int    idx_c;
    float  e0_c, e1_c, e2_c;        // ev of edge (g*16 + r)
    float4 xa_c, xb_c, nr_c;
    int4   dst_c;
    {
        const int e0 = g * 16;
        idx_c = ei[(half >= 2 ? N_EDGES : 0) + e0 + r];
        const float* evp = ev + (size_t)(e0 + r) * 3;
        e0_c = evp[0]; e1_c = evp[1]; e2_c = evp[2];
        nr_c  = *reinterpret_cast<const float4*>(nrm + e0 + half * 4);
        dst_c = *reinterpret_cast<const int4*>(ei + N_EDGES + e0 + half * 4);
        const float4* xr = reinterpret_cast<const float4*>(
            x + (size_t)idx_c * 16 + (half & 1) * 8);
        xa_c = xr[0];
        xb_c = xr[1];
    }

    while (g < ngroups) {
        const int gn    = g + nw;
        const int gsafe = (gn < ngroups) ? gn : g;   // clamp: re-load last group

        // ---- issue NEXT group's independent loads (no exec masking) ----
        const int e0n = gsafe * 16;
        const int   idx_n = ei[(half >= 2 ? N_EDGES : 0) + e0n + r];
        const float* evpn = ev + (size_t)(e0n + r) * 3;
        const float e0_n = evpn[0], e1_n = evpn[1], e2_n = evpn[2];
        const float4 nr_n = *reinterpret_cast<const float4*>(nrm + e0n + half * 4);
        const int4   dst_n = *reinterpret_cast<const int4*>(ei + N_EDGES + e0n + half * 4);

        // ---- h[c] for THIS lane's edge r (once per edge, not per o) ----
        float h[16];
        #pragma unroll
        for (int c = 0; c < 16; ++c) {
            const float hv = fmaf(e2_c, w1c2[c],
                             fmaf(e1_c, w1c1[c],
                             fmaf(e0_c, w1c0[c], b1s[c])));
            h[c] = fmaxf(hv, 0.0f);
        }

        // ---- plain bf16 xe fragment (bias tile A-operand) ----
        bf16x8 afrag;
        afrag[0] = f2bf(xa_c.x); afrag[1] = f2bf(xa_c.y);
        afrag[2] = f2bf(xa_c.z); afrag[3] = f2bf(xa_c.w);
        afrag[4] = f2bf(xb_c.x); afrag[5] = f2bf(xb_c.y);
        afrag[6] = f2bf(xb_c.z); afrag[7] = f2bf(xb_c.w);

        // ---- issue NEXT group's dependent x gather (hides under c-loop) ----
        const float4* xrn = reinterpret_cast<const float4*>(
            x + (size_t)idx_n * 16 + (half & 1) * 8);
        const float4 xa_n = xrn[0];
        const float4 xb_n = xrn[1];

        // ---- bias tile (c=16): acc = xe @ b2^T ----
        f32x4 accA, accB;
        {
            const bf16x8 bfr = *reinterpret_cast<const bf16x8*>(wbase + 16 * 544);
            accA = __builtin_amdgcn_mfma_f32_16x16x32_bf16(
                afrag, bfr, (f32x4){0.f, 0.f, 0.f, 0.f}, 0, 0, 0);
        }
        accB = (f32x4){0.f, 0.f, 0.f, 0.f};

        // ---- 16 c-tiles: A = h[c]*xe (rank-1 YE), accumulate in MFMA ----
        // Two interleaved accumulator chains break the MFMA dependency.
        #pragma unroll
        for (int c = 0; c < 16; ++c) {
            const bf16x8 bfr = *reinterpret_cast<const bf16x8*>(wbase + c * 544);
            const float hc = h[c];
            const float4 y0 = make_float4(hc * xa_c.x, hc * xa_c.y,
                                          hc * xa_c.z, hc * xa_c.w);
            const float4 y1 = make_float4(hc * xb_c.x, hc * xb_c.y,
                                          hc * xb_c.z, hc * xb_c.w);
            bf16x8 yf;
            yf[0] = f2bf(y0.x); yf[1] = f2bf(y0.y);
            yf[2] = f2bf(y0.z); yf[3] = f2bf(y0.w);
            yf[4] = f2bf(y1.x); yf[5] = f2bf(y1.y);
            yf[6] = f2bf(y1.z); yf[7] = f2bf(y1.w);
            if (c & 1)
                accB = __builtin_amdgcn_mfma_f32_16x16x32_bf16(yf, bfr, accB, 0, 0, 0);
            else
                accA = __builtin_amdgcn_mfma_f32_16x16x32_bf16(yf, bfr, accA, 0, 0, 0);
        }

        // ---- epilogue: tanh, norm scale, f32 scatter-add ----
        // D layout (m89-verified): col = l&15 (=o=r), row = half*4+q (=edge)
        const float nrv[4] = {nr_c.x, nr_c.y, nr_c.z, nr_c.w};
        const int   dsv[4] = {dst_c.x, dst_c.y, dst_c.z, dst_c.w};
        #pragma unroll
        for (int q = 0; q < 4; ++q) {
            const float sv = accA[q] + accB[q];
            const float t  = __expf(-2.0f * fabsf(sv));
            const float th = copysignf((1.0f - t) * __builtin_amdgcn_rcpf(1.0f + t), sv);
            atomicAdd(out + (size_t)dsv[q] * 16 + r, th * nrv[q]);
        }

        // ---- rotate pipeline state ----
        idx_c = idx_n;
        e0_c = e0_n; e1_c = e1_n; e2_c = e2_n;
        nr_c  = nr_n;
        dst_c = dst_n;
        xa_c  = xa_n;
        xb_c  = xb_n;
        g = gn;
    }
}

extern "C" void kernel_launch(void* const* d_in, const int* in_sizes, int n_in,
                              void* d_out, int out_size, void* d_ws, size_t ws_size,
                              hipStream_t stream) {
    const float* x   = (const float*)d_in[0];
    const int*   ei  = (const int*)d_in[1];
    const float* ev  = (const float*)d_in[2];
    const float* nrm = (const float*)d_in[3];
    const float* W1  = (const float*)d_in[4];
    const float* b1  = (const float*)d_in[5];
    const float* W2  = (const float*)d_in[6];
    const float* b2  = (const float*)d_in[7];
    float* out = (float*)d_out;

    hipMemsetAsync(out, 0, (size_t)out_size * sizeof(float), stream);

    const int ngroups = N_EDGES / 16;   // 40000, exact
    dim3 grid(2048), block(256);
    hipLaunchKernelGGL(edge_hyper_kernel, grid, block, 0, stream,
                       x, ei, ev, nrm, W1, b1, W2, b2, out, ngroups);
}